// Round 11
// baseline (216.662 us; speedup 1.0000x reference)
//
#include <hip/hip_runtime.h>
#include <hip/hip_fp16.h>
#include <math.h>

// GNO layer, v9b (v9 with compile fix: __builtin_bit_cast instead of
// nonexistent __half2_as_uint):
//   Gp[j,:] = feat[j] @ W1[3:67] + b1 + coords[j] @ W1[0:3]   (fp16, MFMA, sigma-packed)
//   out[i]  = feat[i] @ Ws + bs + b2                           (skip, MFMA)
//   hbar_i  = (1/K) sum_k GELU( Gp[idx[i,k]] - coords[i] @ W1[0:3] )
//   out[i] += hbar_i @ W2                                      (MFMA epilogue)
//
// Gp channel layout sigma: row chunk q (8B) = channels {q, q+16, q+32, q+48}
// so phase1 stores MFMA D-pairs directly; phase2 compensates via indexing only.

#define KNN 16

typedef _Float16 half8 __attribute__((ext_vector_type(8)));
typedef float float4v __attribute__((ext_vector_type(4)));
typedef int int4v __attribute__((ext_vector_type(4)));

__device__ __forceinline__ float lane_bcast(float v, int lane) {
    return __int_as_float(__builtin_amdgcn_readlane(__float_as_int(v), lane));
}

// gelu(x) ~= x * sigmoid(1.5957691*(x + 0.044715 x^3)); exp2-folded constants.
__device__ __forceinline__ float gelu_fast(float x) {
    const float t = x * fmaf(x * x, -0.10294324f, -2.30220821f); // -z*log2(e)
    return x * __builtin_amdgcn_rcpf(1.0f + exp2f(t));
}

// sigma(kp): channel stored at f16-position kp of a Gp row.
__device__ __forceinline__ int sigma_ch(int kp) {
    const int mm = kp >> 1;
    const int base = (mm & 1) ? ((mm >> 1) + 32) : (mm >> 1);
    return base + ((kp & 1) ? 16 : 0);
}

// pack two floats to f16x2 in a uint
__device__ __forceinline__ unsigned int pack_h2(float a, float b) {
    const __half2 h = __floats2half2_rn(a, b);
    return __builtin_bit_cast(unsigned int, h);
}

// Phase 1 v9 (MFMA): per 16-point group, A = feat[16][64] f16 (swizzled LDS),
// 8 MFMAs -> Gp (C-in = b1 + coords@W1p), 8 MFMAs -> out skip (C-in = bs+b2).
__global__ __launch_bounds__(256, 4) void gno_phase1(
    const float* __restrict__ features, const float* __restrict__ coords,
    const float* __restrict__ W1, const float* __restrict__ b1,
    const float* __restrict__ Ws, const float* __restrict__ bs,
    const float* __restrict__ b2, __half* __restrict__ Gp,
    float* __restrict__ out, int n)
{
    __shared__ unsigned short fstage[4][1024];   // per-wave [16 pts][64 ch] f16
    const int c   = threadIdx.x;
    const int p16 = c & 15;
    const int l4  = c >> 4;

    // B-fragments: col = t*16+p16, kp = h*32 + l4*8 + j (natural k order)
    half8 bfG[4][2], bfS[4][2];
    #pragma unroll
    for (int t = 0; t < 4; ++t) {
        const int col = t * 16 + p16;
        #pragma unroll
        for (int h = 0; h < 2; ++h)
            #pragma unroll
            for (int j = 0; j < 8; ++j) {
                const int kp = h * 32 + l4 * 8 + j;
                bfG[t][h][j] = (_Float16)W1[(3 + kp) * 64 + col];
                bfS[t][h][j] = (_Float16)Ws[kp * 64 + col];
            }
    }
    float w1x[4], w1y[4], w1z[4], b1v[4], sbv[4];
    #pragma unroll
    for (int t = 0; t < 4; ++t) {
        const int col = t * 16 + p16;
        w1x[t] = W1[col]; w1y[t] = W1[64 + col]; w1z[t] = W1[128 + col];
        b1v[t] = b1[col]; sbv[t] = bs[col] + b2[col];
    }
    unsigned short* fs = fstage[threadIdx.y];

    const int ngroups = n >> 4;                  // n % 16 == 0
    const int gw = blockIdx.x * 4 + threadIdx.y;
    const int nw = gridDim.x * 4;
    for (int g = gw; g < ngroups; g += nw) {
        const int gbase = g << 4;
        // ---- load 16 feature rows (coalesced), stage as f16 swizzled ----
        float f[16];
        #pragma unroll
        for (int p = 0; p < 16; ++p) f[p] = features[(size_t)(gbase + p) * 64 + c];
        #pragma unroll
        for (int p = 0; p < 16; ++p) {
            const int byte = (p * 128) + ((c * 2) ^ ((p & 7) << 4));
            *(unsigned short*)((char*)fs + byte) =
                __half_as_ushort(__float2half(f[p]));
        }
        // coords of the 16 points: 48 floats in lanes 0..47
        const float cv = (c < 48) ? coords[(size_t)gbase * 3 + c] : 0.0f;

        // ---- A fragments ----
        const int bo0 = (p16 * 128 + l4 * 16) ^ ((p16 & 7) << 4);
        const int bo1 = (p16 * 128 + 64 + l4 * 16) ^ ((p16 & 7) << 4);
        const half8 af0 = *(const half8*)((const char*)fs + bo0);
        const half8 af1 = *(const half8*)((const char*)fs + bo1);

        // ---- C-in for G: b1 + coords@W1p per (row j, col t) ----
        float4v cfG[4];
        #pragma unroll
        for (int j = 0; j < 4; ++j) {
            const int lp = l4 * 4 + j;
            const float cx = __shfl(cv, 3 * lp + 0, 64);
            const float cy = __shfl(cv, 3 * lp + 1, 64);
            const float cz = __shfl(cv, 3 * lp + 2, 64);
            #pragma unroll
            for (int t = 0; t < 4; ++t) {
                float v = fmaf(cx, w1x[t], b1v[t]);
                v = fmaf(cy, w1y[t], v);
                v = fmaf(cz, w1z[t], v);
                cfG[t][j] = v;
            }
        }

        // ---- 16 MFMAs: skip (stored immediately) and G (kept, packed) ----
        float4v dG[4];
        #pragma unroll
        for (int t = 0; t < 4; ++t) {
            float4v cs = {sbv[t], sbv[t], sbv[t], sbv[t]};
            float4v dS = __builtin_amdgcn_mfma_f32_16x16x32_f16(af0, bfS[t][0], cs, 0, 0, 0);
            dS = __builtin_amdgcn_mfma_f32_16x16x32_f16(af1, bfS[t][1], dS, 0, 0, 0);
            float4v dg = __builtin_amdgcn_mfma_f32_16x16x32_f16(af0, bfG[t][0], cfG[t], 0, 0, 0);
            dg = __builtin_amdgcn_mfma_f32_16x16x32_f16(af1, bfG[t][1], dg, 0, 0, 0);
            dG[t] = dg;
            #pragma unroll
            for (int j = 0; j < 4; ++j)
                out[(size_t)(gbase + l4 * 4 + j) * 64 + t * 16 + p16] = dS[j];
        }
        // ---- pack G into sigma layout: chunk p16 = ch {p16,p16+16,p16+32,p16+48} ----
        #pragma unroll
        for (int j = 0; j < 4; ++j) {
            const unsigned long long v =
                (unsigned long long)pack_h2(dG[0][j], dG[1][j]) |
                ((unsigned long long)pack_h2(dG[2][j], dG[3][j]) << 32);
            *(unsigned long long*)((char*)Gp +
                (size_t)(gbase + l4 * 4 + j) * 128 + p16 * 8) = v;
        }
    }
}

// Phase 2 v9: v8 structure; sigma-aware indexing; grid 1563.
__global__ __launch_bounds__(256, 3) void gno_phase2(
    const float* __restrict__ coords, const int* __restrict__ idx,
    const float* __restrict__ W1, const float* __restrict__ W2,
    const __half2* __restrict__ Gp2, float* __restrict__ out, int n)
{
    __shared__ unsigned short w2h[4096];        // W2 as f16
    __shared__ unsigned short hbarall[4][1024]; // per-wave [16 pts][64 ch] f16

    const int tid = threadIdx.y * 64 + threadIdx.x;
    for (int t = tid; t < 4096; t += 256)
        w2h[t] = __half_as_ushort(__float2half(W2[t]));

    const int c   = threadIdx.x;
    const int m   = c & 31;      // gather-pair id
    const int odd = c >> 5;      // 0: even-k neighbors, 1: odd-k
    const int p16 = c & 15;
    const int l4  = c >> 4;
    const int m4  = m * 4;
    // sigma: lane m's gathered half2 = channels {cA, cB}
    const int cA = (m & 1) ? ((m >> 1) + 32) : (m >> 1);
    const int cB = cA + 16;
    const float wx0 = W1[cA],       wx1 = W1[cB];
    const float wy0 = W1[64 + cA],  wy1 = W1[64 + cB];
    const float wz0 = W1[128 + cA], wz1 = W1[128 + cB];
    __syncthreads();

    // B-fragments: k-position kp holds channel sigma_ch(kp) -> W2 row sigma_ch(kp)
    half8 bf[4][2];
    #pragma unroll
    for (int t = 0; t < 4; ++t)
        #pragma unroll
        for (int h = 0; h < 2; ++h)
            #pragma unroll
            for (int j = 0; j < 8; ++j)
                bf[t][h][j] = *(const _Float16*)
                    &w2h[sigma_ch(h * 32 + l4 * 8 + j) * 64 + t * 16 + p16];

    unsigned short* hb = hbarall[threadIdx.y];
    const char* gpb = (const char*)Gp2;

    const int ngroups = n >> 4;            // n % 16 == 0
    const int gw = blockIdx.x * 4 + threadIdx.y;
    const int nw = gridDim.x * 4;
    for (int g = gw; g < ngroups; g += nw) {
        const int gbase = g << 4;
        const int4v vj4 = *(const int4v*)(idx + (size_t)gbase * 16 + c * 4);
        const float cv = (c < 48) ? coords[(size_t)gbase * 3 + c] : 0.0f;

        #pragma unroll
        for (int h = 0; h < 2; ++h) {          // half-group = 8 points
            __half2 gv[4][16];
            #pragma unroll
            for (int pp = 0; pp < 4; ++pp) {
                const int P2 = h * 4 + pp;
                const int e0 = P2 * 32;
                #pragma unroll
                for (int q = 0; q < 8; ++q) {
                    const int ea = e0 + 2 * q,      eb = ea + 1;
                    const int ec = e0 + 16 + 2 * q, ed = ec + 1;
                    const int se = __builtin_amdgcn_readlane(vj4[ea & 3], ea >> 2);
                    const int so = __builtin_amdgcn_readlane(vj4[eb & 3], eb >> 2);
                    const int te = __builtin_amdgcn_readlane(vj4[ec & 3], ec >> 2);
                    const int td = __builtin_amdgcn_readlane(vj4[ed & 3], ed >> 2);
                    const int rA = odd ? so : se;
                    const int rB = odd ? td : te;
                    gv[pp][q]     = *(const __half2*)(gpb + (((unsigned)rA << 7) + m4));
                    gv[pp][8 + q] = *(const __half2*)(gpb + (((unsigned)rB << 7) + m4));
                }
            }
            #pragma unroll
            for (int pp = 0; pp < 4; ++pp) {
                const int P2  = h * 4 + pp;
                const int lp0 = 2 * P2;
                const float a0x = lane_bcast(cv, 3 * lp0 + 0);
                const float a0y = lane_bcast(cv, 3 * lp0 + 1);
                const float a0z = lane_bcast(cv, 3 * lp0 + 2);
                const float a1x = lane_bcast(cv, 3 * lp0 + 3);
                const float a1y = lane_bcast(cv, 3 * lp0 + 4);
                const float a1z = lane_bcast(cv, 3 * lp0 + 5);
                float P00 = a0x * wx0; P00 = fmaf(a0y, wy0, P00); P00 = fmaf(a0z, wz0, P00);
                float P01 = a0x * wx1; P01 = fmaf(a0y, wy1, P01); P01 = fmaf(a0z, wz1, P01);
                float P10 = a1x * wx0; P10 = fmaf(a1y, wy0, P10); P10 = fmaf(a1z, wz0, P10);
                float P11 = a1x * wx1; P11 = fmaf(a1y, wy1, P11); P11 = fmaf(a1z, wz1, P11);

                float a00 = 0.f, a01 = 0.f, a10 = 0.f, a11 = 0.f;
                #pragma unroll
                for (int q = 0; q < 8; ++q) {
                    const float2 xy = __half22float2(gv[pp][q]);
                    a00 += gelu_fast(xy.x - P00);
                    a01 += gelu_fast(xy.y - P01);
                }
                #pragma unroll
                for (int q = 0; q < 8; ++q) {
                    const float2 xy = __half22float2(gv[pp][8 + q]);
                    a10 += gelu_fast(xy.x - P10);
                    a11 += gelu_fast(xy.y - P11);
                }
                a00 *= (1.0f / KNN); a01 *= (1.0f / KNN);
                a10 *= (1.0f / KNN); a11 *= (1.0f / KNN);
                a00 += __shfl_xor(a00, 32, 64);
                a01 += __shfl_xor(a01, 32, 64);
                a10 += __shfl_xor(a10, 32, 64);
                a11 += __shfl_xor(a11, 32, 64);

                const int lp = lp0 + odd;
                const float x0 = odd ? a10 : a00;
                const float x1 = odd ? a11 : a01;
                const unsigned int hh = pack_h2(x0, x1);
                int byte = lp * 128 + m4;
                byte ^= (lp & 7) << 4;               // XOR swizzle (G4)
                *(unsigned int*)((char*)hb + byte) = hh;
            }
        }

        // ---- MFMA epilogue ----
        const int b0 = (p16 * 128 + l4 * 16) ^ ((p16 & 7) << 4);
        const int b1 = (p16 * 128 + 64 + l4 * 16) ^ ((p16 & 7) << 4);
        const half8 af0 = *(const half8*)((const char*)hb + b0);
        const half8 af1 = *(const half8*)((const char*)hb + b1);

        #pragma unroll
        for (int t = 0; t < 4; ++t) {
            float4v cf;
            #pragma unroll
            for (int j = 0; j < 4; ++j)
                cf[j] = out[(size_t)(gbase + l4 * 4 + j) * 64 + t * 16 + p16];
            float4v d = __builtin_amdgcn_mfma_f32_16x16x32_f16(af0, bf[t][0], cf, 0, 0, 0);
            d = __builtin_amdgcn_mfma_f32_16x16x32_f16(af1, bf[t][1], d, 0, 0, 0);
            #pragma unroll
            for (int j = 0; j < 4; ++j)
                out[(size_t)(gbase + l4 * 4 + j) * 64 + t * 16 + p16] = d[j];
        }
    }
}

extern "C" void kernel_launch(void* const* d_in, const int* in_sizes, int n_in,
                              void* d_out, int out_size, void* d_ws, size_t ws_size,
                              hipStream_t stream) {
    const float* coords   = (const float*)d_in[0];
    const float* features = (const float*)d_in[1];
    const int*   idx      = (const int*)d_in[2];
    const float* W1       = (const float*)d_in[3];
    const float* b1       = (const float*)d_in[4];
    const float* W2       = (const float*)d_in[5];
    const float* b2       = (const float*)d_in[6];
    const float* Ws       = (const float*)d_in[7];
    const float* bs       = (const float*)d_in[8];
    float* out = (float*)d_out;
    const int n = in_sizes[0] / 3;            // 100000
    __half* Gp = (__half*)d_ws;               // n*64 halfs = 12.8 MB

    dim3 block(64, 4);
    gno_phase1<<<dim3(782),  block, 0, stream>>>(features, coords, W1, b1,
                                                 Ws, bs, b2, Gp, out, n);
    gno_phase2<<<dim3(1563), block, 0, stream>>>(coords, idx, W1, W2,
                                                 (const __half2*)Gp, out, n);
}